// Round 5
// baseline (177.339 us; speedup 1.0000x reference)
//
#include <hip/hip_runtime.h>
#include <hip/hip_bf16.h>
#include <stdint.h>

typedef __attribute__((ext_vector_type(8))) short s16x8;          // 8 bf16 (4 VGPRs)
typedef __attribute__((ext_vector_type(8))) unsigned short u16x8;
typedef __attribute__((ext_vector_type(4))) float f32x4;

#define D_FEAT 128
#define H2 128
#define BLOCK_THREADS 512
#define WAVES 8
#define MW 32                        // edges per wave (M-tile)
#define EPB (WAVES * MW)             // 256 edges per tile
#define PERSIST_BLOCKS 512           // 2 resident blocks per CU

__device__ __forceinline__ unsigned short f2bf(float f) {
  uint32_t u = __float_as_uint(f);
  return (unsigned short)((u + 0x7fffu + ((u >> 16) & 1u)) >> 16);  // RNE
}

// ---------------- pre-conversion kernels ----------------
__global__ void k_cvt_x(const float* __restrict__ x, unsigned short* __restrict__ xb, int n8) {
  int i = blockIdx.x * blockDim.x + threadIdx.x;
  if (i >= n8) return;
  const f32x4* p = (const f32x4*)x + (size_t)i * 2;
  f32x4 a = p[0], b = p[1];
  u16x8 o;
  o[0] = f2bf(a[0]); o[1] = f2bf(a[1]); o[2] = f2bf(a[2]); o[3] = f2bf(a[3]);
  o[4] = f2bf(b[0]); o[5] = f2bf(b[1]); o[6] = f2bf(b[2]); o[7] = f2bf(b[3]);
  ((u16x8*)xb)[i] = o;
}

// W1 [256][128] fp32 row-major -> swizzled bf16 W1^T tile (64KB) in ws.
// Element (n,k) stored at n*256 + ((chunk ^ (n&7))<<3) + (k&7), chunk = k>>3.
__global__ void k_cvt_w1(const float* __restrict__ W1, unsigned short* __restrict__ w1t) {
  int tid = blockIdx.x * blockDim.x + threadIdx.x;   // 0..4095
  int chunk = tid >> 7;                               // 0..31
  int n = tid & 127;
  u16x8 o;
#pragma unroll
  for (int j = 0; j < 8; ++j)
    o[j] = f2bf(W1[(chunk * 8 + j) * H2 + n]);
  *(u16x8*)(w1t + (n << 8) + ((chunk ^ (n & 7)) << 3)) = o;
}

// ---------------- main fused persistent kernel ----------------
template <bool XBF>
__global__ __launch_bounds__(BLOCK_THREADS, 4)   // 4 waves/SIMD => 2 blocks/CU
void k_edge_mlp(const float* __restrict__ xf,
                const unsigned short* __restrict__ xb,
                const int* __restrict__ eli,      // int32: [2][E]
                const float* __restrict__ W1,
                const unsigned short* __restrict__ w1ws,
                const float* __restrict__ b1,
                const float* __restrict__ W2,
                const float* __restrict__ b2,
                float* __restrict__ out, int E, int nNodes)
{
  __shared__ unsigned short w1t[H2 * 256];   // 64KB, swizzled W1^T
  const int t0   = threadIdx.x;
  const int lane = t0 & 63;
  const int wid  = t0 >> 6;
  const int c    = lane & 15;   // A-row-in-frag / B-col-in-frag
  const int g    = lane >> 4;   // k-subgroup (8 consecutive k)
  const int ch7  = c & 7;

  // ---- stage W1^T (bf16, swizzled) into LDS — ONCE per persistent block ----
  if (XBF) {
#pragma unroll
    for (int i = 0; i < 8; ++i) {
      int idx = i * BLOCK_THREADS + t0;             // 4096 chunks of 16B
      ((u16x8*)w1t)[idx] = ((const u16x8*)w1ws)[idx];
    }
  } else {
    int cg = t0 >> 7;         // 0..3
    int n  = t0 & 127;
#pragma unroll
    for (int i = 0; i < 8; ++i) {
      int ch = cg + 4 * i;    // 0..31
      u16x8 o;
#pragma unroll
      for (int j = 0; j < 8; ++j)
        o[j] = f2bf(W1[(ch * 8 + j) * H2 + n]);
      *(u16x8*)(w1t + (n << 8) + ((ch ^ (n & 7)) << 3)) = o;
    }
  }

  // per-lane B LDS offsets (in shorts): inner ds_read = w1t + boff[kk] + f*4096
  // (f*4096 shorts = 8192B -> compile-time offset immediate, fits 16-bit)
  unsigned boff[8];
#pragma unroll
  for (int kk = 0; kk < 8; ++kk)
    boff[kk] = (unsigned)(c * 256 + (((kk * 4 + g) ^ ch7) << 3));

  __syncthreads();   // the ONLY barrier

  const int nt = (E + EPB - 1) / EPB;
  int t = blockIdx.x;
  if (t >= nt) return;
  const int stride = gridDim.x;

  // load eli for tile tt and produce element offsets into xb/xf (+ g*8 folded in)
  auto mkoff = [&](int tt, unsigned* ro, unsigned* co) {
#pragma unroll
    for (int m = 0; m < 2; ++m) {
      int e = tt * EPB + wid * MW + m * 16 + c;
      e = e < E ? e : E - 1;
      int nr = eli[e];
      int nc = eli[E + e];
      nr = nr < 0 ? 0 : (nr >= nNodes ? nNodes - 1 : nr);   // defensive clamp
      nc = nc < 0 ? 0 : (nc >= nNodes ? nNodes - 1 : nc);
      ro[m] = (unsigned)nr * D_FEAT + g * 8;
      co[m] = (unsigned)nc * D_FEAT + g * 8;
    }
  };

  auto loadA = [&](const unsigned* ro, const unsigned* co, int kk, s16x8* dst) {
#pragma unroll
    for (int m = 0; m < 2; ++m) {
      unsigned off = (kk < 4 ? ro[m] : co[m]) + (unsigned)((kk & 3) * 32);
      if (XBF) {
        dst[m] = *(const s16x8*)(xb + off);
      } else {
        const f32x4* q = (const f32x4*)(xf + off);
        f32x4 a = q[0], b = q[1];
        s16x8 v;
        v[0] = (short)f2bf(a[0]); v[1] = (short)f2bf(a[1]);
        v[2] = (short)f2bf(a[2]); v[3] = (short)f2bf(a[3]);
        v[4] = (short)f2bf(b[0]); v[5] = (short)f2bf(b[1]);
        v[6] = (short)f2bf(b[2]); v[7] = (short)f2bf(b[3]);
        dst[m] = v;
      }
    }
  };

  // prologue: tile t's offsets + first two A-slices in flight
  unsigned ro[2], co[2], ron[2], con[2];
  mkoff(t, ro, co);
  s16x8 abuf[2][2];
  loadA(ro, co, 0, abuf[0]);
  loadA(ro, co, 1, abuf[1]);

  while (true) {
    const int tn = t + stride;
    const bool more = (tn < nt);
    if (more) mkoff(tn, ron, con);   // eli loads for NEXT tile issued early

    f32x4 acc[2][8];
#pragma unroll
    for (int m = 0; m < 2; ++m)
#pragma unroll
      for (int f = 0; f < 8; ++f) {
        f32x4 z = {0.f, 0.f, 0.f, 0.f};
        acc[m][f] = z;
      }

#pragma unroll
    for (int kk = 0; kk < 8; ++kk) {
      __builtin_amdgcn_s_setprio(1);
#pragma unroll
      for (int f = 0; f < 8; ++f) {
        s16x8 bfrag = *(const s16x8*)(w1t + boff[kk] + f * 4096);
#pragma unroll
        for (int m = 0; m < 2; ++m)
          acc[m][f] = __builtin_amdgcn_mfma_f32_16x16x32_bf16(abuf[kk & 1][m], bfrag, acc[m][f], 0, 0, 0);
      }
      __builtin_amdgcn_s_setprio(0);
      if (kk < 6) loadA(ro, co, kk + 2, abuf[kk & 1]);   // refill consumed slot
    }

    // next tile's first gathers in flight during the epilogue
    if (more) {
      loadA(ron, con, 0, abuf[0]);
      loadA(ron, con, 1, abuf[1]);
    }

    // ---- fused epilogue: relu(h + b1) @ W2 + b2, fp32 ----
    float b1v[8], w2v[8];
#pragma unroll
    for (int f = 0; f < 8; ++f) {
      b1v[f] = b1[f * 16 + c];     // L1-resident reloads (saves held regs)
      w2v[f] = W2[f * 16 + c];
    }
    const float b2s = b2[0];

    const int tbase = t * EPB + wid * MW;
#pragma unroll
    for (int m = 0; m < 2; ++m) {
      float sr[4];
#pragma unroll
      for (int r = 0; r < 4; ++r) {
        float s = 0.f;
#pragma unroll
        for (int f = 0; f < 8; ++f) {
          float h = acc[m][f][r] + b1v[f];
          h = h > 0.f ? h : 0.f;
          s += h * w2v[f];
        }
#pragma unroll
        for (int msk = 1; msk < 16; msk <<= 1)
          s += __shfl_xor(s, msk, 64);
        sr[r] = s;
      }
      int ebase = tbase + m * 16 + g * 4;
      if (c == 0 && ebase < E) {
        f32x4 o = {sr[0] + b2s, sr[1] + b2s, sr[2] + b2s, sr[3] + b2s};
        *(f32x4*)(out + ebase) = o;
      }
    }

    if (!more) break;
    t = tn;
#pragma unroll
    for (int m = 0; m < 2; ++m) { ro[m] = ron[m]; co[m] = con[m]; }
  }
}

extern "C" void kernel_launch(void* const* d_in, const int* in_sizes, int n_in,
                              void* d_out, int out_size, void* d_ws, size_t ws_size,
                              hipStream_t stream) {
  const float* x   = (const float*)d_in[0];
  const int*   eli = (const int*)d_in[1];     // int32 per harness contract
  const float* W1  = (const float*)d_in[2];
  const float* b1  = (const float*)d_in[3];
  const float* W2  = (const float*)d_in[4];
  const float* b2  = (const float*)d_in[5];
  float* out = (float*)d_out;

  const int E      = in_sizes[1] / 2;
  const int nNodes = in_sizes[0] / D_FEAT;

  const size_t xbytes = (size_t)nNodes * D_FEAT * 2;   // bf16 copy of x
  const size_t need   = xbytes + 65536;                // + swizzled W1^T
  const bool bfpath   = (ws_size >= need);

  const int nt   = (E + EPB - 1) / EPB;
  const int grid = nt < PERSIST_BLOCKS ? nt : PERSIST_BLOCKS;

  if (bfpath) {
    unsigned short* xbw  = (unsigned short*)d_ws;
    unsigned short* w1tw = (unsigned short*)((char*)d_ws + xbytes);
    int n8 = nNodes * D_FEAT / 8;
    k_cvt_x<<<(n8 + 255) / 256, 256, 0, stream>>>(x, xbw, n8);
    k_cvt_w1<<<16, 256, 0, stream>>>(W1, w1tw);
    k_edge_mlp<true><<<grid, BLOCK_THREADS, 0, stream>>>(
        x, xbw, eli, W1, w1tw, b1, W2, b2, out, E, nNodes);
  } else {
    k_edge_mlp<false><<<grid, BLOCK_THREADS, 0, stream>>>(
        x, nullptr, eli, W1, nullptr, b1, W2, b2, out, E, nNodes);
  }
}